// Round 4
// baseline (188.849 us; speedup 1.0000x reference)
//
#include <hip/hip_runtime.h>
#include <math.h>

typedef unsigned short u16;
typedef unsigned int   u32;
typedef __bf16 bf16x8 __attribute__((ext_vector_type(8)));
typedef float  f32x4  __attribute__((ext_vector_type(4)));
typedef u16    u16x8  __attribute__((ext_vector_type(8)));

#define B_ROWS 16384
#define PC 16
#define EPS_SIM 1e-4f
#define LOG_MIN_F (-18.420680743952367f)
#define KL_IDX  (B_ROWS + B_ROWS * 512)   // 8404992
#define OR_IDX  (KL_IDX + 1)

// direct global->LDS async copy, 16B per lane (lds dest = uniform base + lane*16)
#define GLD16(gp, lp) __builtin_amdgcn_global_load_lds( \
    (const __attribute__((address_space(1))) void*)(gp), \
    (__attribute__((address_space(3))) void*)(lp), 16, 0, 0)

__device__ inline u16 f2bf(float f) {
    u32 u = __float_as_uint(f);
    return (u16)((u + 0x7FFFu + ((u >> 16) & 1u)) >> 16);
}
__device__ inline float bf2f(u16 h) { return __uint_as_float(((u32)h) << 16); }

// ---------------------------------------------------------------------------
__global__ void init_kernel(float* __restrict__ S, float* __restrict__ out)
{
    int i = blockIdx.x * 256 + threadIdx.x;
    if (i < B_ROWS) S[i] = 0.0f;
    if (i == 0) { out[KL_IDX] = 0.0f; out[OR_IDX] = 0.0f; }
}

// fp32 -> (bf16 hi, bf16 lo) arrays, 4 elems/thread
__global__ __launch_bounds__(256)
void split_kernel(const float* __restrict__ src, u16* __restrict__ hi,
                  u16* __restrict__ lo, int n4)
{
    int i = blockIdx.x * 256 + threadIdx.x;
    if (i >= n4) return;
    float4 v = ((const float4*)src)[i];
    float f[4] = {v.x, v.y, v.z, v.w};
    u16 h[4], l[4];
#pragma unroll
    for (int k = 0; k < 4; ++k) {
        h[k] = f2bf(f[k]);
        l[k] = f2bf(f[k] - bf2f(h[k]));
    }
    ((ushort4*)hi)[i] = make_ushort4(h[0], h[1], h[2], h[3]);
    ((ushort4*)lo)[i] = make_ushort4(l[0], l[1], l[2], l[3]);
}

// ---------------------------------------------------------------------------
// Split-bf16 MFMA GEMM: C[M x ldc] = epi(A @ B^T + bias)
// Single 32KB LDS buffer (3 blocks/CU), two-barrier m97-style loop:
//   barrier -> ds_read frags -> barrier -> issue stage(tk+1) -> MFMA
// MODE 0: relu -> split store    MODE 3: tanh -> f32 store
// MODE 4: blockIdx.y<2 -> split store (mu); y>=2 -> logVar S row-reduction
// ---------------------------------------------------------------------------
template<int MODE>
__global__ __launch_bounds__(256, 3)
void gemm_mfma(const u16* __restrict__ Ah_g, const u16* __restrict__ Al_g,
               const u16* __restrict__ Bh_g, const u16* __restrict__ Bl_g,
               const float* __restrict__ bias,
               u16* __restrict__ Ch, u16* __restrict__ Cl,
               float* __restrict__ Cf, float* __restrict__ Srow,
               int K, int ldc)
{
    __shared__ __align__(16) u16 LAh[128][32];
    __shared__ __align__(16) u16 LAl[128][32];
    __shared__ __align__(16) u16 LBh[128][32];
    __shared__ __align__(16) u16 LBl[128][32];

    const int t = threadIdx.x, lane = t & 63, wave = t >> 6;
    const int wm = wave >> 1, wn = wave & 1;
    const int bm = blockIdx.x * 128, bn = blockIdx.y * 128;
    const int rA = lane & 15, g = lane >> 4;

    // staging: lane -> (row-in-16-slab, physical 16B chunk)
    const int srow = lane >> 2, cp = lane & 3;

    f32x4 acc[4][4];
    const f32x4 z4 = {0.f, 0.f, 0.f, 0.f};
#pragma unroll
    for (int i = 0; i < 4; ++i)
#pragma unroll
        for (int j = 0; j < 4; ++j) acc[i][j] = z4;

    auto stage = [&](int kt) {
#pragma unroll
        for (int j = 0; j < 2; ++j) {
            int row = wave * 32 + j * 16 + srow;
            int lc  = (cp - (row >> 1)) & 3;              // inverse swizzle on SOURCE
            size_t goffA = (size_t)(bm + row) * K + kt * 32 + lc * 8;
            size_t goffB = (size_t)(bn + row) * K + kt * 32 + lc * 8;
            GLD16(Ah_g + goffA, &LAh[wave * 32 + j * 16][0]);
            GLD16(Al_g + goffA, &LAl[wave * 32 + j * 16][0]);
            GLD16(Bh_g + goffB, &LBh[wave * 32 + j * 16][0]);
            GLD16(Bl_g + goffB, &LBl[wave * 32 + j * 16][0]);
        }
    };

    const int T = K / 32;
    stage(0);
    for (int tk = 0; tk < T; ++tk) {
        __syncthreads();                 // vmcnt(0) drained: tile tk in LDS

        bf16x8 aH[4], aL[4], bH[4], bL[4];
#pragma unroll
        for (int f = 0; f < 4; ++f) {
            int m  = wm * 64 + f * 16 + rA;
            int cm = ((g + (m >> 1)) & 3) * 8;            // swizzled READ
            aH[f] = *(const bf16x8*)&LAh[m][cm];
            aL[f] = *(const bf16x8*)&LAl[m][cm];
            int n  = wn * 64 + f * 16 + rA;
            int cn = ((g + (n >> 1)) & 3) * 8;
            bH[f] = *(const bf16x8*)&LBh[n][cn];
            bL[f] = *(const bf16x8*)&LBl[n][cn];
        }

        __syncthreads();                 // all reads done; safe to overwrite
        if (tk + 1 < T) stage(tk + 1);   // loads fly during the MFMAs below

#pragma unroll
        for (int i = 0; i < 4; ++i)
#pragma unroll
            for (int j = 0; j < 4; ++j) {
                acc[i][j] = __builtin_amdgcn_mfma_f32_16x16x32_bf16(aH[i], bH[j], acc[i][j], 0, 0, 0);
                acc[i][j] = __builtin_amdgcn_mfma_f32_16x16x32_bf16(aL[i], bH[j], acc[i][j], 0, 0, 0);
                acc[i][j] = __builtin_amdgcn_mfma_f32_16x16x32_bf16(aH[i], bL[j], acc[i][j], 0, 0, 0);
            }
    }

    float bv[4];
#pragma unroll
    for (int j = 0; j < 4; ++j) bv[j] = bias[bn + wn * 64 + j * 16 + rA];

    if (MODE == 4 && blockIdx.y >= 2) {
        // logVar columns: S[row] += mean_l(0.5 e^lv - 0.5 lv - 0.5)
#pragma unroll
        for (int i = 0; i < 4; ++i)
#pragma unroll
            for (int r = 0; r < 4; ++r) {
                int row = bm + wm * 64 + i * 16 + g * 4 + r;
                float s = 0.f;
#pragma unroll
                for (int j = 0; j < 4; ++j) {
                    float lv = acc[i][j][r] + bv[j];
                    lv = fminf(fmaxf(lv, LOG_MIN_F), -LOG_MIN_F);
                    s += 0.5f * __expf(lv) - 0.5f * lv - 0.5f;
                }
                s += __shfl_xor(s, 1, 64); s += __shfl_xor(s, 2, 64);
                s += __shfl_xor(s, 4, 64); s += __shfl_xor(s, 8, 64);
                if (rA == 0) atomicAdd(&Srow[row], s * (1.f / 256.f));
            }
        return;
    }

#pragma unroll
    for (int i = 0; i < 4; ++i)
#pragma unroll
        for (int r = 0; r < 4; ++r) {
            size_t row = bm + wm * 64 + i * 16 + g * 4 + r;
#pragma unroll
            for (int j = 0; j < 4; ++j) {
                int col = bn + wn * 64 + j * 16 + rA;
                float v = acc[i][j][r] + bv[j];
                if (MODE == 0) v = fmaxf(v, 0.f);
                if (MODE == 3) {
                    float e = __expf(2.f * v);
                    Cf[row * ldc + col] = 1.f - 2.f / (e + 1.f);
                } else {
                    u16 hh = f2bf(v);
                    u16 ll = f2bf(v - bf2f(hh));
                    Ch[row * ldc + col] = hh;
                    Cl[row * ldc + col] = ll;
                }
            }
        }
}

// ---------------------------------------------------------------------------
// per-row prototype math: one wave per row, 4 lanes per prototype.
// Each lane privately reduces 64 latent elems (no shfl); 2 shfls finish d^2;
// one 12-shfl cross-proto reduce per row.  (Old version: 96 serial shfls.)
// ---------------------------------------------------------------------------
__global__ __launch_bounds__(256)
void proto_kernel(const u16* __restrict__ mu_h, const u16* __restrict__ mu_l,
                  const float* __restrict__ S, const int* __restrict__ tcls,
                  const float* __restrict__ protos, const float* __restrict__ Wlast,
                  float* __restrict__ out, float* __restrict__ klrow)
{
    int b = (blockIdx.x * 256 + threadIdx.x) >> 6;
    int lane = threadIdx.x & 63;
    int p = lane >> 2, q = lane & 3;

    size_t base = (size_t)b * 256 + q * 64;
    float m[64];
#pragma unroll
    for (int j = 0; j < 8; ++j) {
        u16x8 hh = *(const u16x8*)(mu_h + base + j * 8);
        u16x8 ll = *(const u16x8*)(mu_l + base + j * 8);
#pragma unroll
        for (int e = 0; e < 8; ++e)
            m[j * 8 + e] = bf2f(hh[e]) + bf2f(ll[e]);
    }

    int cls = tcls[b];
    const float* pr = protos + ((size_t)cls * PC + p) * 256 + q * 64;
    float dd = 0.f;
#pragma unroll
    for (int j = 0; j < 16; ++j) {
        float4 pv = *(const float4*)(pr + j * 4);
        float d0 = m[j * 4 + 0] - pv.x;
        float d1 = m[j * 4 + 1] - pv.y;
        float d2 = m[j * 4 + 2] - pv.z;
        float d3 = m[j * 4 + 3] - pv.w;
        dd = fmaf(d0, d0, dd); dd = fmaf(d1, d1, dd);
        dd = fmaf(d2, d2, dd); dd = fmaf(d3, d3, dd);
    }
    dd += __shfl_xor(dd, 1, 64);
    dd += __shfl_xor(dd, 2, 64);         // all 4 lanes of group p hold full d^2

    float d   = sqrtf(dd);
    float sim = __logf((d + 1.0f) / (d + EPS_SIM));
    float kl  = S[b] + dd * (0.5f / 256.f);
    float klw = kl * sim;
    float num  = klw;
    float den  = (klw > 0.0f) ? sim : 0.0f;
    float outv = sim * Wlast[cls * PC + p];

    // values identical within each 4-lane group; reduce across groups only
#pragma unroll
    for (int off = 4; off <= 32; off <<= 1) {
        num  += __shfl_xor(num,  off, 64);
        den  += __shfl_xor(den,  off, 64);
        outv += __shfl_xor(outv, off, 64);
    }
    if (lane == 0) {
        out[b] = outv;
        klrow[b] = num / den;
    }
}

__global__ __launch_bounds__(256)
void reduce_kl(const float* __restrict__ klrow, float* __restrict__ kl_out)
{
    int i = blockIdx.x * 256 + threadIdx.x;
    float v = klrow[i];
#pragma unroll
    for (int off = 32; off; off >>= 1) v += __shfl_xor(v, off, 64);
    __shared__ float red[4];
    int lane = threadIdx.x & 63, w = threadIdx.x >> 6;
    if (lane == 0) red[w] = v;
    __syncthreads();
    if (threadIdx.x == 0)
        atomicAdd(kl_out, (red[0] + red[1] + red[2] + red[3]) * (1.0f / (float)B_ROWS));
}

__global__ __launch_bounds__(256)
void ortho_kernel(const float* __restrict__ protos, float* __restrict__ ortho_out)
{
    int c = blockIdx.x;
    __shared__ float pk[PC][257];
    __shared__ float red[256];
    int t = threadIdx.x;
    for (int i = t; i < PC * 256; i += 256)
        pk[i >> 8][i & 255] = protos[c * PC * 256 + i];
    __syncthreads();
    float mean = 0.0f;
    for (int i = 0; i < PC; ++i) mean += pk[i][t];
    mean *= (1.0f / (float)PC);
    for (int i = 0; i < PC; ++i) pk[i][t] -= mean;
    __syncthreads();
    int i = t >> 4, j = t & 15;
    float gg = 0.0f;
    for (int l = 0; l < 256; ++l) gg += pk[i][l] * pk[j][l];
    gg -= (i == j) ? 1.0f : 0.0f;
    red[t] = gg * gg;
    __syncthreads();
    for (int s = 128; s; s >>= 1) { if (t < s) red[t] += red[t + s]; __syncthreads(); }
    if (t == 0) atomicAdd(ortho_out, sqrtf(red[0]) * (1.0f / 8.0f));
}

// ---------------------------------------------------------------------------
extern "C" void kernel_launch(void* const* d_in, const int* in_sizes, int n_in,
                              void* d_out, int out_size, void* d_ws, size_t ws_size,
                              hipStream_t stream)
{
    const float* x      = (const float*)d_in[0];
    const int*   tcls   = (const int*)  d_in[1];
    const float* protos = (const float*)d_in[2];
    const float* W1     = (const float*)d_in[3];
    const float* b1     = (const float*)d_in[4];
    const float* W2     = (const float*)d_in[5];
    const float* b2     = (const float*)d_in[6];
    const float* Wd1    = (const float*)d_in[7];
    const float* bd1    = (const float*)d_in[8];
    const float* Wd2    = (const float*)d_in[9];
    const float* bd2    = (const float*)d_in[10];
    const float* Wlast  = (const float*)d_in[11];

    float* out     = (float*)d_out;
    float* decoded = out + B_ROWS;

    // h (split bf16) lives in d_out's decoded region (33.55MB), overwritten by G4
    u16* h_h = (u16*)decoded;
    u16* h_l = h_h + 8388608;

    // workspace overlays: x2 region (33.55MB) reused for mu2 + dh2 after G1
    u16* wsu  = (u16*)d_ws;
    u16* x_h  = wsu;
    u16* x_l  = wsu + 8388608;
    u16* mu_h = wsu;
    u16* mu_l = wsu + 4194304;
    u16* dh_h = wsu + 8388608;
    u16* dh_l = wsu + 12582912;

    float* S     = (float*)((char*)d_ws + 33554432);
    float* klrow = S + 16384;
    u16* w = (u16*)(klrow + 16384);
    u16 *W1h = w, *W1l = w + 262144, *W2h = w + 524288, *W2l = w + 786432;
    u16 *Wd1h = w + 1048576, *Wd1l = w + 1114112, *Wd2h = w + 1179648, *Wd2l = w + 1310720;

    hipLaunchKernelGGL(init_kernel, dim3(64), dim3(256), 0, stream, S, out);

    hipLaunchKernelGGL(split_kernel, dim3(8192), dim3(256), 0, stream, x,   x_h,  x_l,  2097152);
    hipLaunchKernelGGL(split_kernel, dim3(256),  dim3(256), 0, stream, W1,  W1h,  W1l,  65536);
    hipLaunchKernelGGL(split_kernel, dim3(256),  dim3(256), 0, stream, W2,  W2h,  W2l,  65536);
    hipLaunchKernelGGL(split_kernel, dim3(64),   dim3(256), 0, stream, Wd1, Wd1h, Wd1l, 16384);
    hipLaunchKernelGGL(split_kernel, dim3(128),  dim3(256), 0, stream, Wd2, Wd2h, Wd2l, 32768);

    // G1: h = relu(x @ W1^T + b1) -> split bf16
    hipLaunchKernelGGL((gemm_mfma<0>), dim3(128, 4), dim3(256), 0, stream,
                       x_h, x_l, W1h, W1l, b1, h_h, h_l, (float*)nullptr, (float*)nullptr, 512, 512);
    // G2: conv = h @ W2^T + b2 -> mu split (y<2) + S row-sums (y>=2)
    hipLaunchKernelGGL((gemm_mfma<4>), dim3(128, 4), dim3(256), 0, stream,
                       h_h, h_l, W2h, W2l, b2, mu_h, mu_l, (float*)nullptr, S, 512, 256);
    // prototype distances, sim, out, per-row kl
    hipLaunchKernelGGL(proto_kernel, dim3(B_ROWS / 4), dim3(256), 0, stream,
                       mu_h, mu_l, S, tcls, protos, Wlast, out, klrow);
    hipLaunchKernelGGL(reduce_kl, dim3(64), dim3(256), 0, stream, klrow, out + KL_IDX);
    // G3: dh = relu(mu @ Wd1^T + bd1) -> split bf16
    hipLaunchKernelGGL((gemm_mfma<0>), dim3(128, 2), dim3(256), 0, stream,
                       mu_h, mu_l, Wd1h, Wd1l, bd1, dh_h, dh_l, (float*)nullptr, (float*)nullptr, 256, 256);
    // G4: decoded = tanh(dh @ Wd2^T + bd2) -> f32 (overwrites h region)
    hipLaunchKernelGGL((gemm_mfma<3>), dim3(128, 4), dim3(256), 0, stream,
                       dh_h, dh_l, Wd2h, Wd2l, bd2, (u16*)nullptr, (u16*)nullptr, decoded, (float*)nullptr, 256, 512);
    hipLaunchKernelGGL(ortho_kernel, dim3(8), dim3(256), 0, stream, protos, out + OR_IDX);
}

// Round 5
// 150.489 us; speedup vs baseline: 1.2549x; 1.2549x over previous
//
#include <hip/hip_runtime.h>
#include <math.h>

typedef unsigned short u16;
typedef unsigned int   u32;
typedef __bf16 bf16x8 __attribute__((ext_vector_type(8)));
typedef float  f32x4  __attribute__((ext_vector_type(4)));

#define B_ROWS 16384
#define PC 16
#define EPS_SIM 1e-4f
#define LOG_MIN_F (-18.420680743952367f)
#define KL_IDX  (B_ROWS + B_ROWS * 512)   // 8404992
#define OR_IDX  (KL_IDX + 1)

// direct global->LDS async copy, 16B per lane (lds dest = uniform base + lane*16)
#define GLD16(gp, lp) __builtin_amdgcn_global_load_lds( \
    (const __attribute__((address_space(1))) void*)(gp), \
    (__attribute__((address_space(3))) void*)(lp), 16, 0, 0)

__device__ inline u16 f2bf(float f) {
    u32 u = __float_as_uint(f);
    return (u16)((u + 0x7FFFu + ((u >> 16) & 1u)) >> 16);
}
__device__ inline float bf2f(u16 h) { return __uint_as_float(((u32)h) << 16); }

// ---------------------------------------------------------------------------
__global__ void init_kernel(float* __restrict__ S, float* __restrict__ Mn,
                            float* __restrict__ out)
{
    int i = blockIdx.x * 256 + threadIdx.x;
    if (i < B_ROWS) { S[i] = 0.0f; Mn[i] = 0.0f; }
    if (i == 0) { out[KL_IDX] = 0.0f; out[OR_IDX] = 0.0f; }
}

// fp32 -> (bf16 hi, bf16 lo) arrays, 4 elems/thread
__global__ __launch_bounds__(256)
void split_kernel(const float* __restrict__ src, u16* __restrict__ hi,
                  u16* __restrict__ lo, int n4)
{
    int i = blockIdx.x * 256 + threadIdx.x;
    if (i >= n4) return;
    float4 v = ((const float4*)src)[i];
    float f[4] = {v.x, v.y, v.z, v.w};
    u16 h[4], l[4];
#pragma unroll
    for (int k = 0; k < 4; ++k) {
        h[k] = f2bf(f[k]);
        l[k] = f2bf(f[k] - bf2f(h[k]));
    }
    ((ushort4*)hi)[i] = make_ushort4(h[0], h[1], h[2], h[3]);
    ((ushort4*)lo)[i] = make_ushort4(l[0], l[1], l[2], l[3]);
}

// pnorm[p] = |protos[p]|^2 ; 512 threads, 4 lanes per proto row
__global__ __launch_bounds__(256)
void pnorm_kernel(const float* __restrict__ protos, float* __restrict__ pnorm)
{
    int t = blockIdx.x * 256 + threadIdx.x;
    int row = t >> 2, q = t & 3;
    const float* pr = protos + (size_t)row * 256 + q * 64;
    float s = 0.f;
#pragma unroll
    for (int j = 0; j < 16; ++j) {
        float4 v = *(const float4*)(pr + j * 4);
        s = fmaf(v.x, v.x, s); s = fmaf(v.y, v.y, s);
        s = fmaf(v.z, v.z, s); s = fmaf(v.w, v.w, s);
    }
    s += __shfl_xor(s, 1, 64);
    s += __shfl_xor(s, 2, 64);
    if (q == 0) pnorm[row] = s;
}

// ---------------------------------------------------------------------------
// Split-bf16 MFMA GEMM: C[M x ldc] = epi(A @ B^T + bias)
// Single 32KB LDS buffer, two-barrier loop (stage(tk+1) flies under MFMAs).
// MODE 0: relu -> split store    MODE 3: tanh -> f32 store
// MODE 4: blockIdx.y<2 -> split store (mu) + munorm row-reduce; y>=2 -> S
// ---------------------------------------------------------------------------
template<int MODE>
__global__ __launch_bounds__(256, 3)
void gemm_mfma(const u16* __restrict__ Ah_g, const u16* __restrict__ Al_g,
               const u16* __restrict__ Bh_g, const u16* __restrict__ Bl_g,
               const float* __restrict__ bias,
               u16* __restrict__ Ch, u16* __restrict__ Cl,
               float* __restrict__ Cf, float* __restrict__ Srow,
               float* __restrict__ Mnorm, int K, int ldc)
{
    __shared__ __align__(16) u16 LAh[128][32];
    __shared__ __align__(16) u16 LAl[128][32];
    __shared__ __align__(16) u16 LBh[128][32];
    __shared__ __align__(16) u16 LBl[128][32];

    const int t = threadIdx.x, lane = t & 63, wave = t >> 6;
    const int wm = wave >> 1, wn = wave & 1;
    const int bm = blockIdx.x * 128, bn = blockIdx.y * 128;
    const int rA = lane & 15, g = lane >> 4;
    const int srow = lane >> 2, cp = lane & 3;

    f32x4 acc[4][4];
    const f32x4 z4 = {0.f, 0.f, 0.f, 0.f};
#pragma unroll
    for (int i = 0; i < 4; ++i)
#pragma unroll
        for (int j = 0; j < 4; ++j) acc[i][j] = z4;

    auto stage = [&](int kt) {
#pragma unroll
        for (int j = 0; j < 2; ++j) {
            int row = wave * 32 + j * 16 + srow;
            int lc  = (cp - (row >> 1)) & 3;              // inverse swizzle on SOURCE
            size_t goffA = (size_t)(bm + row) * K + kt * 32 + lc * 8;
            size_t goffB = (size_t)(bn + row) * K + kt * 32 + lc * 8;
            GLD16(Ah_g + goffA, &LAh[wave * 32 + j * 16][0]);
            GLD16(Al_g + goffA, &LAl[wave * 32 + j * 16][0]);
            GLD16(Bh_g + goffB, &LBh[wave * 32 + j * 16][0]);
            GLD16(Bl_g + goffB, &LBl[wave * 32 + j * 16][0]);
        }
    };

    const int T = K / 32;
    stage(0);
    for (int tk = 0; tk < T; ++tk) {
        __syncthreads();                 // vmcnt(0) drained: tile tk in LDS

        bf16x8 aH[4], aL[4], bH[4], bL[4];
#pragma unroll
        for (int f = 0; f < 4; ++f) {
            int m  = wm * 64 + f * 16 + rA;
            int cm = ((g + (m >> 1)) & 3) * 8;            // swizzled READ
            aH[f] = *(const bf16x8*)&LAh[m][cm];
            aL[f] = *(const bf16x8*)&LAl[m][cm];
            int n  = wn * 64 + f * 16 + rA;
            int cn = ((g + (n >> 1)) & 3) * 8;
            bH[f] = *(const bf16x8*)&LBh[n][cn];
            bL[f] = *(const bf16x8*)&LBl[n][cn];
        }

        __syncthreads();                 // all reads done; safe to overwrite
        if (tk + 1 < T) stage(tk + 1);   // loads fly during the MFMAs below

#pragma unroll
        for (int i = 0; i < 4; ++i)
#pragma unroll
            for (int j = 0; j < 4; ++j) {
                acc[i][j] = __builtin_amdgcn_mfma_f32_16x16x32_bf16(aH[i], bH[j], acc[i][j], 0, 0, 0);
                acc[i][j] = __builtin_amdgcn_mfma_f32_16x16x32_bf16(aL[i], bH[j], acc[i][j], 0, 0, 0);
                acc[i][j] = __builtin_amdgcn_mfma_f32_16x16x32_bf16(aH[i], bL[j], acc[i][j], 0, 0, 0);
            }
    }

    float bv[4];
#pragma unroll
    for (int j = 0; j < 4; ++j) bv[j] = bias[bn + wn * 64 + j * 16 + rA];

    if (MODE == 4 && blockIdx.y >= 2) {
        // logVar columns: S[row] += mean_l(0.5 e^lv - 0.5 lv - 0.5)
#pragma unroll
        for (int i = 0; i < 4; ++i)
#pragma unroll
            for (int r = 0; r < 4; ++r) {
                int row = bm + wm * 64 + i * 16 + g * 4 + r;
                float s = 0.f;
#pragma unroll
                for (int j = 0; j < 4; ++j) {
                    float lv = acc[i][j][r] + bv[j];
                    lv = fminf(fmaxf(lv, LOG_MIN_F), -LOG_MIN_F);
                    s += 0.5f * __expf(lv) - 0.5f * lv - 0.5f;
                }
                s += __shfl_xor(s, 1, 64); s += __shfl_xor(s, 2, 64);
                s += __shfl_xor(s, 4, 64); s += __shfl_xor(s, 8, 64);
                if (rA == 0) atomicAdd(&Srow[row], s * (1.f / 256.f));
            }
        return;
    }

#pragma unroll
    for (int i = 0; i < 4; ++i)
#pragma unroll
        for (int r = 0; r < 4; ++r) {
            size_t row = bm + wm * 64 + i * 16 + g * 4 + r;
            float sq = 0.f;
#pragma unroll
            for (int j = 0; j < 4; ++j) {
                int col = bn + wn * 64 + j * 16 + rA;
                float v = acc[i][j][r] + bv[j];
                if (MODE == 0) v = fmaxf(v, 0.f);
                if (MODE == 3) {
                    float e = __expf(2.f * v);
                    Cf[row * ldc + col] = 1.f - 2.f / (e + 1.f);
                } else {
                    u16 hh = f2bf(v);
                    u16 ll = f2bf(v - bf2f(hh));
                    Ch[row * ldc + col] = hh;
                    Cl[row * ldc + col] = ll;
                    if (MODE == 4) sq = fmaf(v, v, sq);
                }
            }
            if (MODE == 4) {   // |mu|^2 partial for this wave-column's 64 cols
                sq += __shfl_xor(sq, 1, 64); sq += __shfl_xor(sq, 2, 64);
                sq += __shfl_xor(sq, 4, 64); sq += __shfl_xor(sq, 8, 64);
                if (rA == 0) atomicAdd(&Mnorm[row], sq);
            }
        }
}

// ---------------------------------------------------------------------------
// proto distance GEMM: cross[b,p] = mu[b] . proto[p]  (M=16384, N=128, K=256)
// Fused epilogue: d^2 = munorm + pnorm - 2*cross; sim/kl/out for the
// contiguous class slab cols cls*16..cls*16+15 (one j-block of one wave-col).
// ---------------------------------------------------------------------------
__global__ __launch_bounds__(256, 3)
void proto_gemm(const u16* __restrict__ Ah_g, const u16* __restrict__ Al_g,
                const u16* __restrict__ Bh_g, const u16* __restrict__ Bl_g,
                const int* __restrict__ tcls, const float* __restrict__ Mnorm,
                const float* __restrict__ pnorm, const float* __restrict__ S,
                const float* __restrict__ Wlast,
                float* __restrict__ out, float* __restrict__ klrow)
{
    __shared__ __align__(16) u16 LAh[128][32];
    __shared__ __align__(16) u16 LAl[128][32];
    __shared__ __align__(16) u16 LBh[128][32];
    __shared__ __align__(16) u16 LBl[128][32];

    const int t = threadIdx.x, lane = t & 63, wave = t >> 6;
    const int wm = wave >> 1, wn = wave & 1;
    const int bm = blockIdx.x * 128;
    const int rA = lane & 15, g = lane >> 4;
    const int srow = lane >> 2, cp = lane & 3;
    const int K = 256;

    f32x4 acc[4][4];
    const f32x4 z4 = {0.f, 0.f, 0.f, 0.f};
#pragma unroll
    for (int i = 0; i < 4; ++i)
#pragma unroll
        for (int j = 0; j < 4; ++j) acc[i][j] = z4;

    auto stage = [&](int kt) {
#pragma unroll
        for (int j = 0; j < 2; ++j) {
            int row = wave * 32 + j * 16 + srow;
            int lc  = (cp - (row >> 1)) & 3;
            size_t goffA = (size_t)(bm + row) * K + kt * 32 + lc * 8;
            size_t goffB = (size_t)row * K + kt * 32 + lc * 8;
            GLD16(Ah_g + goffA, &LAh[wave * 32 + j * 16][0]);
            GLD16(Al_g + goffA, &LAl[wave * 32 + j * 16][0]);
            GLD16(Bh_g + goffB, &LBh[wave * 32 + j * 16][0]);
            GLD16(Bl_g + goffB, &LBl[wave * 32 + j * 16][0]);
        }
    };

    stage(0);
    for (int tk = 0; tk < 8; ++tk) {
        __syncthreads();
        bf16x8 aH[4], aL[4], bH[4], bL[4];
#pragma unroll
        for (int f = 0; f < 4; ++f) {
            int m  = wm * 64 + f * 16 + rA;
            int cm = ((g + (m >> 1)) & 3) * 8;
            aH[f] = *(const bf16x8*)&LAh[m][cm];
            aL[f] = *(const bf16x8*)&LAl[m][cm];
            int n  = wn * 64 + f * 16 + rA;
            int cn = ((g + (n >> 1)) & 3) * 8;
            bH[f] = *(const bf16x8*)&LBh[n][cn];
            bL[f] = *(const bf16x8*)&LBl[n][cn];
        }
        __syncthreads();
        if (tk + 1 < 8) stage(tk + 1);
#pragma unroll
        for (int i = 0; i < 4; ++i)
#pragma unroll
            for (int j = 0; j < 4; ++j) {
                acc[i][j] = __builtin_amdgcn_mfma_f32_16x16x32_bf16(aH[i], bH[j], acc[i][j], 0, 0, 0);
                acc[i][j] = __builtin_amdgcn_mfma_f32_16x16x32_bf16(aL[i], bH[j], acc[i][j], 0, 0, 0);
                acc[i][j] = __builtin_amdgcn_mfma_f32_16x16x32_bf16(aH[i], bL[j], acc[i][j], 0, 0, 0);
            }
    }

    float pn[4], wl[4];
#pragma unroll
    for (int j = 0; j < 4; ++j) {
        int col = wn * 64 + j * 16 + rA;
        pn[j] = pnorm[col];
        wl[j] = Wlast[col];
    }

#pragma unroll
    for (int i = 0; i < 4; ++i)
#pragma unroll
        for (int r = 0; r < 4; ++r) {
            int row = bm + wm * 64 + i * 16 + g * 4 + r;
            int cls = tcls[row];
            int jsel = cls & 3;
            bool owner = ((cls >> 2) == wn);
            float cv = 0.f, pnv = 0.f, wlv = 0.f;
#pragma unroll
            for (int j = 0; j < 4; ++j) {
                bool sel = (j == jsel);
                cv  = sel ? acc[i][j][r] : cv;
                pnv = sel ? pn[j] : pnv;
                wlv = sel ? wl[j] : wlv;
            }
            float dd  = fmaxf(Mnorm[row] + pnv - 2.f * cv, 0.f);
            float d   = sqrtf(dd);
            float sim = __logf((d + 1.0f) / (d + EPS_SIM));
            float kl  = S[row] + dd * (0.5f / 256.f);
            float klw = kl * sim;
            float num = klw;
            float den = (klw > 0.0f) ? sim : 0.0f;
            float ov  = sim * wlv;
            num += __shfl_xor(num, 1, 64); den += __shfl_xor(den, 1, 64); ov += __shfl_xor(ov, 1, 64);
            num += __shfl_xor(num, 2, 64); den += __shfl_xor(den, 2, 64); ov += __shfl_xor(ov, 2, 64);
            num += __shfl_xor(num, 4, 64); den += __shfl_xor(den, 4, 64); ov += __shfl_xor(ov, 4, 64);
            num += __shfl_xor(num, 8, 64); den += __shfl_xor(den, 8, 64); ov += __shfl_xor(ov, 8, 64);
            if (owner && rA == 0) {
                out[row]   = ov;
                klrow[row] = num / den;
            }
        }
}

__global__ __launch_bounds__(256)
void reduce_kl(const float* __restrict__ klrow, float* __restrict__ kl_out)
{
    int i = blockIdx.x * 256 + threadIdx.x;
    float v = klrow[i];
#pragma unroll
    for (int off = 32; off; off >>= 1) v += __shfl_xor(v, off, 64);
    __shared__ float red[4];
    int lane = threadIdx.x & 63, w = threadIdx.x >> 6;
    if (lane == 0) red[w] = v;
    __syncthreads();
    if (threadIdx.x == 0)
        atomicAdd(kl_out, (red[0] + red[1] + red[2] + red[3]) * (1.0f / (float)B_ROWS));
}

__global__ __launch_bounds__(256)
void ortho_kernel(const float* __restrict__ protos, float* __restrict__ ortho_out)
{
    int c = blockIdx.x;
    __shared__ float pk[PC][257];
    __shared__ float red[256];
    int t = threadIdx.x;
    for (int i = t; i < PC * 256; i += 256)
        pk[i >> 8][i & 255] = protos[c * PC * 256 + i];
    __syncthreads();
    float mean = 0.0f;
    for (int i = 0; i < PC; ++i) mean += pk[i][t];
    mean *= (1.0f / (float)PC);
    for (int i = 0; i < PC; ++i) pk[i][t] -= mean;
    __syncthreads();
    int i = t >> 4, j = t & 15;
    float gg = 0.0f;
    for (int l = 0; l < 256; ++l) gg += pk[i][l] * pk[j][l];
    gg -= (i == j) ? 1.0f : 0.0f;
    red[t] = gg * gg;
    __syncthreads();
    for (int s = 128; s; s >>= 1) { if (t < s) red[t] += red[t + s]; __syncthreads(); }
    if (t == 0) atomicAdd(ortho_out, sqrtf(red[0]) * (1.0f / 8.0f));
}

// ---------------------------------------------------------------------------
extern "C" void kernel_launch(void* const* d_in, const int* in_sizes, int n_in,
                              void* d_out, int out_size, void* d_ws, size_t ws_size,
                              hipStream_t stream)
{
    const float* x      = (const float*)d_in[0];
    const int*   tcls   = (const int*)  d_in[1];
    const float* protos = (const float*)d_in[2];
    const float* W1     = (const float*)d_in[3];
    const float* b1     = (const float*)d_in[4];
    const float* W2     = (const float*)d_in[5];
    const float* b2     = (const float*)d_in[6];
    const float* Wd1    = (const float*)d_in[7];
    const float* bd1    = (const float*)d_in[8];
    const float* Wd2    = (const float*)d_in[9];
    const float* bd2    = (const float*)d_in[10];
    const float* Wlast  = (const float*)d_in[11];

    float* out     = (float*)d_out;
    float* decoded = out + B_ROWS;

    // h (split bf16) lives in d_out's decoded region (33.55MB), overwritten by G4
    u16* h_h = (u16*)decoded;
    u16* h_l = h_h + 8388608;

    // workspace overlays: x region (32MB) reused for mu + dh after G1
    u16* wsu  = (u16*)d_ws;
    u16* x_h  = wsu;
    u16* x_l  = wsu + 8388608;
    u16* mu_h = wsu;
    u16* mu_l = wsu + 4194304;
    u16* dh_h = wsu + 8388608;
    u16* dh_l = wsu + 12582912;

    float* S     = (float*)((char*)d_ws + 33554432);
    float* klrow = S + 16384;
    u16* w = (u16*)(klrow + 16384);
    u16 *W1h = w, *W1l = w + 262144, *W2h = w + 524288, *W2l = w + 786432;
    u16 *Wd1h = w + 1048576, *Wd1l = w + 1114112, *Wd2h = w + 1179648, *Wd2l = w + 1310720;
    u16 *ph = w + 1441792, *pl = ph + 32768;       // protos split (128x256)
    float* munorm = (float*)(pl + 32768);          // 16384 f32
    float* pnorm  = munorm + 16384;                // 128 f32

    hipLaunchKernelGGL(init_kernel, dim3(64), dim3(256), 0, stream, S, munorm, out);

    hipLaunchKernelGGL(split_kernel, dim3(8192), dim3(256), 0, stream, x,   x_h,  x_l,  2097152);
    hipLaunchKernelGGL(split_kernel, dim3(256),  dim3(256), 0, stream, W1,  W1h,  W1l,  65536);
    hipLaunchKernelGGL(split_kernel, dim3(256),  dim3(256), 0, stream, W2,  W2h,  W2l,  65536);
    hipLaunchKernelGGL(split_kernel, dim3(64),   dim3(256), 0, stream, Wd1, Wd1h, Wd1l, 16384);
    hipLaunchKernelGGL(split_kernel, dim3(128),  dim3(256), 0, stream, Wd2, Wd2h, Wd2l, 32768);
    hipLaunchKernelGGL(split_kernel, dim3(32),   dim3(256), 0, stream, protos, ph, pl, 8192);
    hipLaunchKernelGGL(pnorm_kernel, dim3(2),    dim3(256), 0, stream, protos, pnorm);

    // G1: h = relu(x @ W1^T + b1) -> split bf16
    hipLaunchKernelGGL((gemm_mfma<0>), dim3(128, 4), dim3(256), 0, stream,
                       x_h, x_l, W1h, W1l, b1, h_h, h_l, (float*)nullptr, (float*)nullptr,
                       (float*)nullptr, 512, 512);
    // G2: conv = h @ W2^T + b2 -> mu split + munorm (y<2); S row-sums (y>=2)
    hipLaunchKernelGGL((gemm_mfma<4>), dim3(128, 4), dim3(256), 0, stream,
                       h_h, h_l, W2h, W2l, b2, mu_h, mu_l, (float*)nullptr, S, munorm, 512, 256);
    // proto distances via MFMA + fused sim/kl epilogue
    hipLaunchKernelGGL(proto_gemm, dim3(128), dim3(256), 0, stream,
                       mu_h, mu_l, ph, pl, tcls, munorm, pnorm, S, Wlast, out, klrow);
    hipLaunchKernelGGL(reduce_kl, dim3(64), dim3(256), 0, stream, klrow, out + KL_IDX);
    // G3: dh = relu(mu @ Wd1^T + bd1) -> split bf16
    hipLaunchKernelGGL((gemm_mfma<0>), dim3(128, 2), dim3(256), 0, stream,
                       mu_h, mu_l, Wd1h, Wd1l, bd1, dh_h, dh_l, (float*)nullptr, (float*)nullptr,
                       (float*)nullptr, 256, 256);
    // G4: decoded = tanh(dh @ Wd2^T + bd2) -> f32 (overwrites h region)
    hipLaunchKernelGGL((gemm_mfma<3>), dim3(128, 4), dim3(256), 0, stream,
                       dh_h, dh_l, Wd2h, Wd2l, bd2, (u16*)nullptr, (u16*)nullptr, decoded,
                       (float*)nullptr, (float*)nullptr, 256, 512);
    hipLaunchKernelGGL(ortho_kernel, dim3(8), dim3(256), 0, stream, protos, out + OR_IDX);
}